// Round 5
// baseline (503.877 us; speedup 1.0000x reference)
//
#include <hip/hip_runtime.h>
#include <hip/hip_bf16.h>

#define T_TOK 3136
#define DDIM  1024
#define HDIM  768
#define NEXP  23
#define TOPK  3
#define MTILE 128
#define NTILE 128
#define KTILE 32
#define LDSP  40            // padded LDS row stride (bf16): 80B rows keep 16B align, reads ~2-way (free)
#define MAX_TILES_PER_E 25  // ceil(3136/128)
#define MAX_SLOTS 16384     // >= 12329 (routed, 128-padded) + 3200 (shared padded)
#define GATE_BLOCKS 1568    // 2 tokens per block, grid-stride

typedef __attribute__((ext_vector_type(8))) short  short8;   // 8 bf16 = 16B (MFMA A/B frag / staging)
typedef __attribute__((ext_vector_type(4))) short  short4v;
typedef __attribute__((ext_vector_type(2))) short  short2v;
typedef __attribute__((ext_vector_type(4))) float  floatx4;  // MFMA C/D frag

__device__ __forceinline__ short f2b(float f) {  // fp32 -> bf16, round-to-nearest-even
    union { float f; unsigned u; } v; v.f = f;
    unsigned r = v.u + 0x7FFFu + ((v.u >> 16) & 1u);
    return (short)(r >> 16);
}
__device__ __forceinline__ float b2f(short s) {
    union { unsigned u; float f; } v; v.u = ((unsigned)(unsigned short)s) << 16; return v.f;
}
__device__ __forceinline__ float gelu_exact(float v) {
    return 0.5f * v * (1.0f + erff(v * 0.70710678118654752f));
}

// ---------------- gate_w transpose: gw [DDIM][NEXP] -> gwT [24][DDIM] (fp32, row 23 zeroed) ----------------
__global__ __launch_bounds__(256) void gwt_kernel(const float* __restrict__ gw, float* __restrict__ gwT) {
    __shared__ float tile[32][33];
    const int kt = blockIdx.x;                       // 32 k-rows per block
    const int tx = threadIdx.x & 31, ty = threadIdx.x >> 5;
    #pragma unroll
    for (int i = 0; i < 4; i++) {
        int k = ty + i * 8;                          // local k row
        tile[k][tx] = (tx < NEXP) ? gw[(size_t)(kt * 32 + k) * NEXP + tx] : 0.f;
    }
    __syncthreads();
    #pragma unroll
    for (int i = 0; i < 4; i++) {
        int e = ty + i * 8;
        if (e < 24) gwT[(size_t)e * DDIM + kt * 32 + tx] = tile[tx][e];  // e=23 -> zeros (pad expert)
    }
}

// ---------------- weight prep: fp32 [k][n] -> bf16 [n][k], all 4 weight groups ----------------
__global__ __launch_bounds__(256) void prep_w_kernel(
    const float* __restrict__ w1, const float* __restrict__ ws1,
    const float* __restrict__ w2, const float* __restrict__ ws2,
    short* __restrict__ w1t, short* __restrict__ ws1t,
    short* __restrict__ w2t, short* __restrict__ ws2t)
{
    const int z = blockIdx.z;
    const float* src; short* dst; int SK, SN;
    if (z < NEXP + 1) {                 // w1 group: src [DDIM][HDIM] -> dst [HDIM][DDIM]
        src = (z < NEXP) ? w1 + (size_t)z * DDIM * HDIM : ws1;
        dst = (z < NEXP) ? w1t + (size_t)z * DDIM * HDIM : ws1t;
        SK = DDIM; SN = HDIM;
    } else {                            // w2 group: src [HDIM][DDIM] -> dst [DDIM][HDIM]
        int e = z - (NEXP + 1);
        src = (e < NEXP) ? w2 + (size_t)e * DDIM * HDIM : ws2;
        dst = (e < NEXP) ? w2t + (size_t)e * DDIM * HDIM : ws2t;
        SK = HDIM; SN = DDIM;
    }
    const int nt = blockIdx.x, kt = blockIdx.y;
    if (nt * 32 >= SN || kt * 64 >= SK) return;
    __shared__ float tile[64][33];
    const int tx = threadIdx.x & 31, ty = threadIdx.x >> 5;   // ty 0..7
    #pragma unroll
    for (int i = 0; i < 8; i++)
        tile[ty + i * 8][tx] = src[(size_t)(kt * 64 + ty + i * 8) * SN + nt * 32 + tx];
    __syncthreads();
    #pragma unroll
    for (int i = 0; i < 4; i++) {      // short2 (4B) contiguous writes, 128B per wave-row
        int n = ty + i * 8;
        short2v sv = { f2b(tile[2 * tx][n]), f2b(tile[2 * tx + 1][n]) };
        *(short2v*)&dst[(size_t)(nt * 32 + n) * SK + kt * 64 + 2 * tx] = sv;
    }
}

// ---------------- x -> bf16 ----------------
__global__ __launch_bounds__(256) void xcvt_kernel(const float* __restrict__ x, short* __restrict__ xb) {
    int i = blockIdx.x * 256 + threadIdx.x;           // float4 index, grid covers T*D/4 exactly
    float4 v = ((const float4*)x)[i];
    short4v s = { f2b(v.x), f2b(v.y), f2b(v.z), f2b(v.w) };
    ((short4v*)xb)[i] = s;
}

// ---------------- gate: grid-stride 2 tokens/block, 4 waves x 6 experts, float4 loads ----------------
__global__ __launch_bounds__(256) void gate_kernel(
    const float* __restrict__ x, const float* __restrict__ gwT, const float* __restrict__ gb,
    float* __restrict__ gwn, int* __restrict__ top_idx, float* __restrict__ top_w,
    int* __restrict__ counts)
{
    const int tid = threadIdx.x;
    const int lane = tid & 63, wave = tid >> 6;
    const int ebase = wave * 6;                      // waves cover experts 0..23 (23 = zero pad)
    __shared__ float sg[24];

    for (int t = blockIdx.x; t < T_TOK; t += GATE_BLOCKS) {
        const float4* xr4 = (const float4*)(x + (size_t)t * DDIM);
        float4 xv[4];
        #pragma unroll
        for (int j = 0; j < 4; j++) xv[j] = xr4[j * 64 + lane];

        // 6 independent fp64 chains; per j-step 6 independent float4 loads (wide MLP)
        double a0 = 0, a1 = 0, a2 = 0, a3 = 0, a4 = 0, a5 = 0;
        #pragma unroll
        for (int j = 0; j < 4; j++) {
            const float4* gp = (const float4*)gwT + (size_t)ebase * 256 + j * 64 + lane;
            float4 g0 = gp[0 * 256], g1 = gp[1 * 256], g2 = gp[2 * 256];
            float4 g3 = gp[3 * 256], g4 = gp[4 * 256], g5 = gp[5 * 256];
            float4 xj = xv[j];
            a0 += (double)xj.x * g0.x + (double)xj.y * g0.y + (double)xj.z * g0.z + (double)xj.w * g0.w;
            a1 += (double)xj.x * g1.x + (double)xj.y * g1.y + (double)xj.z * g1.z + (double)xj.w * g1.w;
            a2 += (double)xj.x * g2.x + (double)xj.y * g2.y + (double)xj.z * g2.z + (double)xj.w * g2.w;
            a3 += (double)xj.x * g3.x + (double)xj.y * g3.y + (double)xj.z * g3.z + (double)xj.w * g3.w;
            a4 += (double)xj.x * g4.x + (double)xj.y * g4.y + (double)xj.z * g4.z + (double)xj.w * g4.w;
            a5 += (double)xj.x * g5.x + (double)xj.y * g5.y + (double)xj.z * g5.z + (double)xj.w * g5.w;
        }
        #pragma unroll
        for (int off = 32; off > 0; off >>= 1) {     // interleaved butterflies (6-wide ILP)
            a0 += __shfl_xor(a0, off);
            a1 += __shfl_xor(a1, off);
            a2 += __shfl_xor(a2, off);
            a3 += __shfl_xor(a3, off);
            a4 += __shfl_xor(a4, off);
            a5 += __shfl_xor(a5, off);
        }

        if (lane == 0) {
            double av[6] = { a0, a1, a2, a3, a4, a5 };
            #pragma unroll
            for (int i = 0; i < 6; i++) {
                int e = ebase + i;
                if (e < NEXP) {
                    float z = (float)av[i] + gb[e];
                    sg[e] = 1.0f / (1.0f + expf(-z));
                }
            }
        }
        __syncthreads();

        if (tid < NEXP) {
            float s = 0.f;
            #pragma unroll
            for (int e = 0; e < NEXP; e++) s += sg[e];
            gwn[(size_t)t * NEXP + tid] = sg[tid] / s;
        }
        if (tid == 0) {
            float v0 = -1.f, v1 = -1.f, v2 = -1.f; int i0 = 0, i1 = 0, i2 = 0;
            for (int e = 0; e < NEXP; e++) {
                float v = sg[e];
                if (v > v0)      { v2 = v1; i2 = i1; v1 = v0; i1 = i0; v0 = v; i0 = e; }
                else if (v > v1) { v2 = v1; i2 = i1; v1 = v; i1 = e; }
                else if (v > v2) { v2 = v; i2 = e; }
            }
            float ts = v0 + v1 + v2;
            top_idx[t * 3 + 0] = i0; top_w[t * 3 + 0] = v0 / ts;
            top_idx[t * 3 + 1] = i1; top_w[t * 3 + 1] = v1 / ts;
            top_idx[t * 3 + 2] = i2; top_w[t * 3 + 2] = v2 / ts;
            atomicAdd(&counts[i0], 1); atomicAdd(&counts[i1], 1); atomicAdd(&counts[i2], 1);
        }
        __syncthreads();   // sg reused next token iteration
    }
}

// ---------------- offsets (128-padded per-expert slot ranges) + slot init ----------------
__global__ __launch_bounds__(256) void offsets_kernel(
    const int* __restrict__ counts, int* __restrict__ offs, int* __restrict__ ntl,
    int* __restrict__ slot_t)
{
    if (threadIdx.x == 0) {
        int o = 0;
        for (int e = 0; e < NEXP; e++) {
            int nt = (counts[e] + MTILE - 1) / MTILE;
            ntl[e] = nt; offs[e] = o; o += nt * MTILE;
        }
        ntl[NEXP] = (T_TOK + MTILE - 1) / MTILE;  // shared expert: all tokens
        offs[NEXP] = o; o += ntl[NEXP] * MTILE;
        offs[NEXP + 1] = o;
    }
    for (int i = threadIdx.x; i < MAX_SLOTS; i += 256) slot_t[i] = 0;  // pad slots -> token 0
}

// ---------------- scatter tokens into expert buckets ----------------
__global__ __launch_bounds__(256) void scatter_kernel(
    const int* __restrict__ top_idx, const int* __restrict__ offs, int* __restrict__ fill,
    int* __restrict__ slot_t, int* __restrict__ slot_of)
{
    int t = blockIdx.x * blockDim.x + threadIdx.x;
    if (t >= T_TOK) return;
    #pragma unroll
    for (int k = 0; k < TOPK; k++) {
        int e = top_idx[t * 3 + k];
        int pos = atomicAdd(&fill[e], 1);
        int s = offs[e] + pos;
        slot_t[s] = t;
        slot_of[t * 4 + k] = s;
    }
    int s = offs[NEXP] + t;  // shared expert bucket
    slot_t[s] = t;
    slot_of[t * 4 + 3] = s;
}

// ---------------- GEMM1: hh[slot][h] = gelu(xb[tok] @ W1t^T + b1), bf16 out ----------------
__global__ __launch_bounds__(256) void gemm1_kernel(
    const short* __restrict__ xb,
    const short* __restrict__ w1t, const float* __restrict__ b1,
    const short* __restrict__ ws1t, const float* __restrict__ bs1,
    const int* __restrict__ ntl, const int* __restrict__ offs,
    const int* __restrict__ slot_t, short* __restrict__ hh)
{
    const int e = blockIdx.z;
    if ((int)blockIdx.y >= ntl[e]) return;
    const int slot_base = offs[e] + blockIdx.y * MTILE;
    const int n0 = blockIdx.x * NTILE;
    const short* __restrict__ W  = (e < NEXP) ? (w1t + (size_t)e * DDIM * HDIM) : ws1t;  // [HDIM][DDIM]
    const float* __restrict__ Bv = (e < NEXP) ? (b1 + (size_t)e * HDIM) : bs1;

    __shared__ __align__(16) short As[MTILE * LDSP];
    __shared__ __align__(16) short Bs[NTILE * LDSP];
    __shared__ int toks[MTILE];

    const int tid = threadIdx.x;
    for (int i = tid; i < MTILE; i += 256) toks[i] = slot_t[slot_base + i];

    const int lane = tid & 63, wave = tid >> 6;
    const int mbase = (wave & 1) * 64, nbase = (wave >> 1) * 64;
    const int lc = lane & 15, q = lane >> 4;
    const int sr = tid >> 2, sc = (tid & 3) * 8;   // staging: 4 threads/row, 16B each

    floatx4 acc[4][4];
    #pragma unroll
    for (int m = 0; m < 4; m++)
        #pragma unroll
        for (int n = 0; n < 4; n++) acc[m][n] = (floatx4)0.f;

    __syncthreads();

    for (int k0 = 0; k0 < DDIM; k0 += KTILE) {
        #pragma unroll
        for (int pp = 0; pp < 2; pp++) {
            int row = sr + pp * 64;
            *(short8*)&As[row * LDSP + sc] =
                *(const short8*)(xb + (size_t)toks[row] * DDIM + k0 + sc);
            *(short8*)&Bs[row * LDSP + sc] =
                *(const short8*)(W + (size_t)(n0 + row) * DDIM + k0 + sc);
        }
        __syncthreads();
        short8 af[4], bf[4];
        #pragma unroll
        for (int m = 0; m < 4; m++) af[m] = *(const short8*)&As[(mbase + m * 16 + lc) * LDSP + q * 8];
        #pragma unroll
        for (int n = 0; n < 4; n++) bf[n] = *(const short8*)&Bs[(nbase + n * 16 + lc) * LDSP + q * 8];
        #pragma unroll
        for (int m = 0; m < 4; m++)
            #pragma unroll
            for (int n = 0; n < 4; n++)
                acc[m][n] = __builtin_amdgcn_mfma_f32_16x16x32_bf16(af[m], bf[n], acc[m][n], 0, 0, 0);
        __syncthreads();
    }

    #pragma unroll
    for (int n = 0; n < 4; n++) {
        const int col = n0 + nbase + n * 16 + lc;
        const float bb = Bv[col];
        #pragma unroll
        for (int m = 0; m < 4; m++) {
            const int rbase = slot_base + mbase + m * 16 + q * 4;
            #pragma unroll
            for (int r = 0; r < 4; r++) {
                float v = acc[m][n][r] + bb;
                hh[(size_t)(rbase + r) * HDIM + col] = f2b(gelu_exact(v));
            }
        }
    }
}

// ---------------- GEMM2: eo[slot][d] = hh[slot] @ W2t^T + b2 (bf16, unweighted) ----------------
__global__ __launch_bounds__(256) void gemm2_kernel(
    const short* __restrict__ hh,
    const short* __restrict__ w2t, const float* __restrict__ b2,
    const short* __restrict__ ws2t, const float* __restrict__ bs2,
    const int* __restrict__ ntl, const int* __restrict__ offs,
    short* __restrict__ eo)
{
    const int e = blockIdx.z;
    if ((int)blockIdx.y >= ntl[e]) return;
    const int slot_base = offs[e] + blockIdx.y * MTILE;
    const int n0 = blockIdx.x * NTILE;
    const short* __restrict__ W  = (e < NEXP) ? (w2t + (size_t)e * HDIM * DDIM) : ws2t;  // [DDIM][HDIM]
    const float* __restrict__ Bv = (e < NEXP) ? (b2 + (size_t)e * DDIM) : bs2;

    __shared__ __align__(16) short As[MTILE * LDSP];
    __shared__ __align__(16) short Bs[NTILE * LDSP];

    const int tid = threadIdx.x;
    const int lane = tid & 63, wave = tid >> 6;
    const int mbase = (wave & 1) * 64, nbase = (wave >> 1) * 64;
    const int lc = lane & 15, q = lane >> 4;
    const int sr = tid >> 2, sc = (tid & 3) * 8;

    floatx4 acc[4][4];
    #pragma unroll
    for (int m = 0; m < 4; m++)
        #pragma unroll
        for (int n = 0; n < 4; n++) acc[m][n] = (floatx4)0.f;

    for (int k0 = 0; k0 < HDIM; k0 += KTILE) {
        #pragma unroll
        for (int pp = 0; pp < 2; pp++) {
            int row = sr + pp * 64;
            *(short8*)&As[row * LDSP + sc] =
                *(const short8*)(hh + (size_t)(slot_base + row) * HDIM + k0 + sc);
            *(short8*)&Bs[row * LDSP + sc] =
                *(const short8*)(W + (size_t)(n0 + row) * HDIM + k0 + sc);
        }
        __syncthreads();
        short8 af[4], bf[4];
        #pragma unroll
        for (int m = 0; m < 4; m++) af[m] = *(const short8*)&As[(mbase + m * 16 + lc) * LDSP + q * 8];
        #pragma unroll
        for (int n = 0; n < 4; n++) bf[n] = *(const short8*)&Bs[(nbase + n * 16 + lc) * LDSP + q * 8];
        #pragma unroll
        for (int m = 0; m < 4; m++)
            #pragma unroll
            for (int n = 0; n < 4; n++)
                acc[m][n] = __builtin_amdgcn_mfma_f32_16x16x32_bf16(af[m], bf[n], acc[m][n], 0, 0, 0);
        __syncthreads();
    }

    #pragma unroll
    for (int n = 0; n < 4; n++) {
        const int col = n0 + nbase + n * 16 + lc;
        const float bb = Bv[col];
        #pragma unroll
        for (int m = 0; m < 4; m++) {
            const int rbase = slot_base + mbase + m * 16 + q * 4;
            #pragma unroll
            for (int r = 0; r < 4; r++)
                eo[(size_t)(rbase + r) * DDIM + col] = f2b(acc[m][n][r] + bb);
        }
    }
}

// ---------------- combine: out[t] = eo[shared] + sum_k tw_k * eo[slot_k] ----------------
__global__ __launch_bounds__(256) void combine_kernel(
    const short* __restrict__ eo, const float* __restrict__ top_w,
    const int* __restrict__ slot_of, float* __restrict__ out)
{
    const int t = blockIdx.x;
    const int c = threadIdx.x * 4;
    const int s0 = slot_of[t * 4 + 0], s1 = slot_of[t * 4 + 1];
    const int s2 = slot_of[t * 4 + 2], s3 = slot_of[t * 4 + 3];
    const float w0 = top_w[t * 3 + 0], w1 = top_w[t * 3 + 1], w2 = top_w[t * 3 + 2];
    short4v a = *(const short4v*)(eo + (size_t)s0 * DDIM + c);
    short4v b = *(const short4v*)(eo + (size_t)s1 * DDIM + c);
    short4v d = *(const short4v*)(eo + (size_t)s2 * DDIM + c);
    short4v s = *(const short4v*)(eo + (size_t)s3 * DDIM + c);
    float4 o;
    o.x = b2f(s.x) + w0 * b2f(a.x) + w1 * b2f(b.x) + w2 * b2f(d.x);
    o.y = b2f(s.y) + w0 * b2f(a.y) + w1 * b2f(b.y) + w2 * b2f(d.y);
    o.z = b2f(s.z) + w0 * b2f(a.z) + w1 * b2f(b.z) + w2 * b2f(d.z);
    o.w = b2f(s.w) + w0 * b2f(a.w) + w1 * b2f(b.w) + w2 * b2f(d.w);
    *(float4*)(out + (size_t)t * DDIM + c) = o;
}

// ---------------- aux loss ----------------
__global__ __launch_bounds__(256) void preduce_kernel(const float* __restrict__ gwn, float* __restrict__ Pf) {
    __shared__ float sP[NEXP];
    if (threadIdx.x < NEXP) sP[threadIdx.x] = 0.f;
    __syncthreads();
    int t = blockIdx.x * blockDim.x + threadIdx.x;
    if (t < T_TOK) {
        #pragma unroll
        for (int e = 0; e < NEXP; e++) atomicAdd(&sP[e], gwn[(size_t)t * NEXP + e]);
    }
    __syncthreads();
    if (threadIdx.x < NEXP) atomicAdd(&Pf[threadIdx.x], sP[threadIdx.x]);
}

__global__ void aux_kernel(const float* __restrict__ Pf, const int* __restrict__ counts,
                           float* __restrict__ out_aux) {
    if (threadIdx.x == 0 && blockIdx.x == 0) {
        float aux = 0.f;
        for (int e = 0; e < NEXP; e++) {
            float P = Pf[e] / (float)T_TOK;
            float F = (float)NEXP * (float)counts[e] / (float)(TOPK * T_TOK);
            aux += P * F;
        }
        out_aux[0] = aux;
    }
}

extern "C" void kernel_launch(void* const* d_in, const int* in_sizes, int n_in,
                              void* d_out, int out_size, void* d_ws, size_t ws_size,
                              hipStream_t stream)
{
    const float* x   = (const float*)d_in[0];
    const float* gw  = (const float*)d_in[1];
    const float* gb  = (const float*)d_in[2];
    const float* w1  = (const float*)d_in[3];
    const float* b1  = (const float*)d_in[4];
    const float* w2  = (const float*)d_in[5];
    const float* b2  = (const float*)d_in[6];
    const float* ws1 = (const float*)d_in[7];
    const float* bs1 = (const float*)d_in[8];
    const float* ws2 = (const float*)d_in[9];
    const float* bs2 = (const float*)d_in[10];
    float* out = (float*)d_out;

    char* p = (char*)d_ws;
    auto alloc = [&](size_t bytes) -> char* {
        char* r = p; p += (bytes + 255) & ~(size_t)255; return r;
    };
    float* gwn     = (float*)alloc((size_t)T_TOK * NEXP * 4);
    int*   top_idx = (int*)  alloc((size_t)T_TOK * 3 * 4);
    float* top_w   = (float*)alloc((size_t)T_TOK * 3 * 4);
    int*   meta    = (int*)  alloc(3 * NEXP * 4);   // counts | fill | Pf (one memset)
    int*   counts  = meta;
    int*   fill    = meta + NEXP;
    float* Pf      = (float*)(meta + 2 * NEXP);
    int*   offs    = (int*)  alloc((NEXP + 2) * 4);
    int*   ntl     = (int*)  alloc((NEXP + 1) * 4);
    int*   slot_t  = (int*)  alloc((size_t)MAX_SLOTS * 4);
    int*   slot_of = (int*)  alloc((size_t)T_TOK * 4 * 4);
    float* gwT     = (float*)alloc((size_t)24 * DDIM * 4);     // 24 rows: expert 23 = zero pad
    short* xb      = (short*)alloc((size_t)T_TOK * DDIM * 2);
    short* w1t     = (short*)alloc((size_t)NEXP * DDIM * HDIM * 2);
    short* ws1t    = (short*)alloc((size_t)DDIM * HDIM * 2);
    short* w2t     = (short*)alloc((size_t)NEXP * DDIM * HDIM * 2);
    short* ws2t    = (short*)alloc((size_t)DDIM * HDIM * 2);
    short* hh      = (short*)alloc((size_t)MAX_SLOTS * HDIM * 2);
    short* eo      = (short*)alloc((size_t)MAX_SLOTS * DDIM * 2);

    hipMemsetAsync(meta, 0, 3 * NEXP * 4, stream);

    gwt_kernel<<<DDIM / 32, 256, 0, stream>>>(gw, gwT);
    prep_w_kernel<<<dim3(32, 16, 2 * (NEXP + 1)), 256, 0, stream>>>(
        w1, ws1, w2, ws2, w1t, ws1t, w2t, ws2t);
    xcvt_kernel<<<(T_TOK * DDIM / 4) / 256, 256, 0, stream>>>(x, xb);
    gate_kernel<<<GATE_BLOCKS, 256, 0, stream>>>(x, gwT, gb, gwn, top_idx, top_w, counts);
    offsets_kernel<<<1, 256, 0, stream>>>(counts, offs, ntl, slot_t);
    scatter_kernel<<<(T_TOK + 255) / 256, 256, 0, stream>>>(top_idx, offs, fill, slot_t, slot_of);
    gemm1_kernel<<<dim3(HDIM / NTILE, MAX_TILES_PER_E, NEXP + 1), 256, 0, stream>>>(
        xb, w1t, b1, ws1t, bs1, ntl, offs, slot_t, hh);
    gemm2_kernel<<<dim3(DDIM / NTILE, MAX_TILES_PER_E, NEXP + 1), 256, 0, stream>>>(
        hh, w2t, b2, ws2t, bs2, ntl, offs, eo);
    combine_kernel<<<T_TOK, 256, 0, stream>>>(eo, top_w, slot_of, out);
    preduce_kernel<<<(T_TOK + 255) / 256, 256, 0, stream>>>(gwn, Pf);
    aux_kernel<<<1, 64, 0, stream>>>(Pf, counts, out + (size_t)T_TOK * DDIM);
}

// Round 6
// 440.536 us; speedup vs baseline: 1.1438x; 1.1438x over previous
//
#include <hip/hip_runtime.h>
#include <hip/hip_bf16.h>

#define T_TOK 3136
#define DDIM  1024
#define HDIM  768
#define NEXP  23
#define TOPK  3
#define MTILE 128
#define NTILE 128
#define KTILE 32
#define LDSP  40            // padded LDS row stride (bf16): 80B rows keep 16B align, reads ~2-way (free)
#define MAX_TILES_PER_E 25  // ceil(3136/128)
#define MAX_SLOTS 16384     // >= 12329 (routed, 128-padded) + 3200 (shared padded)
#define GATE_BLOCKS 1568    // 2 tokens per block, grid-stride
#define NBLK_T 13           // ceil(3136/256) token blocks for hist/scatter

typedef __attribute__((ext_vector_type(8))) short  short8;   // 8 bf16 = 16B (MFMA A/B frag / staging)
typedef __attribute__((ext_vector_type(4))) short  short4v;
typedef __attribute__((ext_vector_type(2))) short  short2v;
typedef __attribute__((ext_vector_type(4))) float  floatx4;  // MFMA C/D frag

__device__ __forceinline__ short f2b(float f) {  // fp32 -> bf16, round-to-nearest-even
    union { float f; unsigned u; } v; v.f = f;
    unsigned r = v.u + 0x7FFFu + ((v.u >> 16) & 1u);
    return (short)(r >> 16);
}
__device__ __forceinline__ float b2f(short s) {
    union { unsigned u; float f; } v; v.u = ((unsigned)(unsigned short)s) << 16; return v.f;
}
__device__ __forceinline__ float gelu_exact(float v) {
    return 0.5f * v * (1.0f + erff(v * 0.70710678118654752f));
}

// ---------------- gate_w transpose: gw [DDIM][NEXP] -> gwT [24][DDIM] (fp32, row 23 zeroed) ----------------
__global__ __launch_bounds__(256) void gwt_kernel(const float* __restrict__ gw, float* __restrict__ gwT) {
    __shared__ float tile[32][33];
    const int kt = blockIdx.x;                       // 32 k-rows per block
    const int tx = threadIdx.x & 31, ty = threadIdx.x >> 5;
    #pragma unroll
    for (int i = 0; i < 4; i++) {
        int k = ty + i * 8;                          // local k row
        tile[k][tx] = (tx < NEXP) ? gw[(size_t)(kt * 32 + k) * NEXP + tx] : 0.f;
    }
    __syncthreads();
    #pragma unroll
    for (int i = 0; i < 4; i++) {
        int e = ty + i * 8;
        if (e < 24) gwT[(size_t)e * DDIM + kt * 32 + tx] = tile[tx][e];  // e=23 -> zeros (pad expert)
    }
}

// ---------------- weight prep: fp32 [k][n] -> bf16 [n][k], all 4 weight groups ----------------
__global__ __launch_bounds__(256) void prep_w_kernel(
    const float* __restrict__ w1, const float* __restrict__ ws1,
    const float* __restrict__ w2, const float* __restrict__ ws2,
    short* __restrict__ w1t, short* __restrict__ ws1t,
    short* __restrict__ w2t, short* __restrict__ ws2t)
{
    const int z = blockIdx.z;
    const float* src; short* dst; int SK, SN;
    if (z < NEXP + 1) {                 // w1 group: src [DDIM][HDIM] -> dst [HDIM][DDIM]
        src = (z < NEXP) ? w1 + (size_t)z * DDIM * HDIM : ws1;
        dst = (z < NEXP) ? w1t + (size_t)z * DDIM * HDIM : ws1t;
        SK = DDIM; SN = HDIM;
    } else {                            // w2 group: src [HDIM][DDIM] -> dst [DDIM][HDIM]
        int e = z - (NEXP + 1);
        src = (e < NEXP) ? w2 + (size_t)e * DDIM * HDIM : ws2;
        dst = (e < NEXP) ? w2t + (size_t)e * DDIM * HDIM : ws2t;
        SK = HDIM; SN = DDIM;
    }
    const int nt = blockIdx.x, kt = blockIdx.y;
    if (nt * 32 >= SN || kt * 64 >= SK) return;
    __shared__ float tile[64][33];
    const int tx = threadIdx.x & 31, ty = threadIdx.x >> 5;   // ty 0..7
    #pragma unroll
    for (int i = 0; i < 8; i++)
        tile[ty + i * 8][tx] = src[(size_t)(kt * 64 + ty + i * 8) * SN + nt * 32 + tx];
    __syncthreads();
    #pragma unroll
    for (int i = 0; i < 4; i++) {      // short2 (4B) contiguous writes, 128B per wave-row
        int n = ty + i * 8;
        short2v sv = { f2b(tile[2 * tx][n]), f2b(tile[2 * tx + 1][n]) };
        *(short2v*)&dst[(size_t)(nt * 32 + n) * SK + kt * 64 + 2 * tx] = sv;
    }
}

// ---------------- x -> bf16 ----------------
__global__ __launch_bounds__(256) void xcvt_kernel(const float* __restrict__ x, short* __restrict__ xb) {
    int i = blockIdx.x * 256 + threadIdx.x;           // float4 index, grid covers T*D/4 exactly
    float4 v = ((const float4*)x)[i];
    short4v s = { f2b(v.x), f2b(v.y), f2b(v.z), f2b(v.w) };
    ((short4v*)xb)[i] = s;
}

// ---------------- gate: grid-stride 2 tokens/block, 4 waves x 6 experts, NO global atomics ----------------
__global__ __launch_bounds__(256) void gate_kernel(
    const float* __restrict__ x, const float* __restrict__ gwT, const float* __restrict__ gb,
    float* __restrict__ gwn, int* __restrict__ top_idx, float* __restrict__ top_w)
{
    const int tid = threadIdx.x;
    const int lane = tid & 63, wave = tid >> 6;
    const int ebase = wave * 6;                      // waves cover experts 0..23 (23 = zero pad)
    __shared__ float sg[24];

    for (int t = blockIdx.x; t < T_TOK; t += GATE_BLOCKS) {
        const float4* xr4 = (const float4*)(x + (size_t)t * DDIM);
        float4 xv[4];
        #pragma unroll
        for (int j = 0; j < 4; j++) xv[j] = xr4[j * 64 + lane];

        // 6 independent fp64 chains; per j-step 6 independent float4 loads
        double a0 = 0, a1 = 0, a2 = 0, a3 = 0, a4 = 0, a5 = 0;
        #pragma unroll
        for (int j = 0; j < 4; j++) {
            const float4* gp = (const float4*)gwT + (size_t)ebase * 256 + j * 64 + lane;
            float4 g0 = gp[0 * 256], g1 = gp[1 * 256], g2 = gp[2 * 256];
            float4 g3 = gp[3 * 256], g4 = gp[4 * 256], g5 = gp[5 * 256];
            float4 xj = xv[j];
            a0 += (double)xj.x * g0.x + (double)xj.y * g0.y + (double)xj.z * g0.z + (double)xj.w * g0.w;
            a1 += (double)xj.x * g1.x + (double)xj.y * g1.y + (double)xj.z * g1.z + (double)xj.w * g1.w;
            a2 += (double)xj.x * g2.x + (double)xj.y * g2.y + (double)xj.z * g2.z + (double)xj.w * g2.w;
            a3 += (double)xj.x * g3.x + (double)xj.y * g3.y + (double)xj.z * g3.z + (double)xj.w * g3.w;
            a4 += (double)xj.x * g4.x + (double)xj.y * g4.y + (double)xj.z * g4.z + (double)xj.w * g4.w;
            a5 += (double)xj.x * g5.x + (double)xj.y * g5.y + (double)xj.z * g5.z + (double)xj.w * g5.w;
        }
        #pragma unroll
        for (int off = 32; off > 0; off >>= 1) {     // interleaved butterflies (6-wide ILP)
            a0 += __shfl_xor(a0, off);
            a1 += __shfl_xor(a1, off);
            a2 += __shfl_xor(a2, off);
            a3 += __shfl_xor(a3, off);
            a4 += __shfl_xor(a4, off);
            a5 += __shfl_xor(a5, off);
        }

        if (lane == 0) {
            double av[6] = { a0, a1, a2, a3, a4, a5 };
            #pragma unroll
            for (int i = 0; i < 6; i++) {
                int e = ebase + i;
                if (e < NEXP) {
                    float z = (float)av[i] + gb[e];
                    sg[e] = 1.0f / (1.0f + expf(-z));
                }
            }
        }
        __syncthreads();

        if (tid < NEXP) {
            float s = 0.f;
            #pragma unroll
            for (int e = 0; e < NEXP; e++) s += sg[e];
            gwn[(size_t)t * NEXP + tid] = sg[tid] / s;
        }
        if (tid == 0) {
            float v0 = -1.f, v1 = -1.f, v2 = -1.f; int i0 = 0, i1 = 0, i2 = 0;
            for (int e = 0; e < NEXP; e++) {
                float v = sg[e];
                if (v > v0)      { v2 = v1; i2 = i1; v1 = v0; i1 = i0; v0 = v; i0 = e; }
                else if (v > v1) { v2 = v1; i2 = i1; v1 = v; i1 = e; }
                else if (v > v2) { v2 = v; i2 = e; }
            }
            float ts = v0 + v1 + v2;
            top_idx[t * 3 + 0] = i0; top_w[t * 3 + 0] = v0 / ts;
            top_idx[t * 3 + 1] = i1; top_w[t * 3 + 1] = v1 / ts;
            top_idx[t * 3 + 2] = i2; top_w[t * 3 + 2] = v2 / ts;
        }
        __syncthreads();   // sg reused next token iteration
    }
}

// ---------------- histogram: per-block LDS hist -> block_hist + counts (299 atomics total) ----------------
__global__ __launch_bounds__(256) void hist_kernel(
    const int* __restrict__ top_idx, int* __restrict__ block_hist, int* __restrict__ counts)
{
    __shared__ int h[NEXP];
    const int b = blockIdx.x, tid = threadIdx.x;
    if (tid < NEXP) h[tid] = 0;
    __syncthreads();
    int t = b * 256 + tid;
    if (t < T_TOK) {
        atomicAdd(&h[top_idx[t * 3 + 0]], 1);
        atomicAdd(&h[top_idx[t * 3 + 1]], 1);
        atomicAdd(&h[top_idx[t * 3 + 2]], 1);
    }
    __syncthreads();
    if (tid < NEXP) {
        block_hist[b * NEXP + tid] = h[tid];
        atomicAdd(&counts[tid], h[tid]);
    }
}

// ---------------- offsets + per-block bases + slot init ----------------
__global__ __launch_bounds__(256) void offsets_kernel(
    const int* __restrict__ counts, const int* __restrict__ block_hist,
    int* __restrict__ offs, int* __restrict__ ntl, int* __restrict__ block_base,
    int* __restrict__ slot_t)
{
    __shared__ int soffs[NEXP + 1];
    if (threadIdx.x == 0) {
        int o = 0;
        for (int e = 0; e < NEXP; e++) {
            int nt = (counts[e] + MTILE - 1) / MTILE;
            ntl[e] = nt; offs[e] = o; soffs[e] = o; o += nt * MTILE;
        }
        ntl[NEXP] = (T_TOK + MTILE - 1) / MTILE;  // shared expert: all tokens
        offs[NEXP] = o; soffs[NEXP] = o; o += ntl[NEXP] * MTILE;
        offs[NEXP + 1] = o;
    }
    __syncthreads();
    if (threadIdx.x < NEXP) {
        int e = threadIdx.x;
        int run = soffs[e];
        for (int b = 0; b < NBLK_T; b++) {           // exclusive prefix of block hists
            block_base[b * NEXP + e] = run;
            run += block_hist[b * NEXP + e];
        }
    }
    for (int i = threadIdx.x; i < MAX_SLOTS; i += 256) slot_t[i] = 0;  // pad slots -> token 0
}

// ---------------- scatter: LDS fill counters, zero global atomics ----------------
__global__ __launch_bounds__(256) void scatter_kernel(
    const int* __restrict__ top_idx, const int* __restrict__ offs,
    const int* __restrict__ block_base,
    int* __restrict__ slot_t, int* __restrict__ slot_of)
{
    __shared__ int lfill[NEXP];
    const int b = blockIdx.x, tid = threadIdx.x;
    if (tid < NEXP) lfill[tid] = 0;
    __syncthreads();
    int t = b * 256 + tid;
    if (t < T_TOK) {
        #pragma unroll
        for (int k = 0; k < TOPK; k++) {
            int e = top_idx[t * 3 + k];
            int pos = atomicAdd(&lfill[e], 1);       // block-local LDS atomic
            int s = block_base[b * NEXP + e] + pos;
            slot_t[s] = t;
            slot_of[t * 4 + k] = s;
        }
        int s = offs[NEXP] + t;                      // shared expert bucket (no atomic)
        slot_t[s] = t;
        slot_of[t * 4 + 3] = s;
    }
}

// ---------------- GEMM1: hh[slot][h] = gelu(xb[tok] @ W1t^T + b1), bf16 out ----------------
__global__ __launch_bounds__(256) void gemm1_kernel(
    const short* __restrict__ xb,
    const short* __restrict__ w1t, const float* __restrict__ b1,
    const short* __restrict__ ws1t, const float* __restrict__ bs1,
    const int* __restrict__ ntl, const int* __restrict__ offs,
    const int* __restrict__ slot_t, short* __restrict__ hh)
{
    const int e = blockIdx.z;
    if ((int)blockIdx.y >= ntl[e]) return;
    const int slot_base = offs[e] + blockIdx.y * MTILE;
    const int n0 = blockIdx.x * NTILE;
    const short* __restrict__ W  = (e < NEXP) ? (w1t + (size_t)e * DDIM * HDIM) : ws1t;  // [HDIM][DDIM]
    const float* __restrict__ Bv = (e < NEXP) ? (b1 + (size_t)e * HDIM) : bs1;

    __shared__ __align__(16) short As[MTILE * LDSP];
    __shared__ __align__(16) short Bs[NTILE * LDSP];
    __shared__ int toks[MTILE];

    const int tid = threadIdx.x;
    for (int i = tid; i < MTILE; i += 256) toks[i] = slot_t[slot_base + i];

    const int lane = tid & 63, wave = tid >> 6;
    const int mbase = (wave & 1) * 64, nbase = (wave >> 1) * 64;
    const int lc = lane & 15, q = lane >> 4;
    const int sr = tid >> 2, sc = (tid & 3) * 8;   // staging: 4 threads/row, 16B each

    floatx4 acc[4][4];
    #pragma unroll
    for (int m = 0; m < 4; m++)
        #pragma unroll
        for (int n = 0; n < 4; n++) acc[m][n] = (floatx4)0.f;

    __syncthreads();

    for (int k0 = 0; k0 < DDIM; k0 += KTILE) {
        #pragma unroll
        for (int pp = 0; pp < 2; pp++) {
            int row = sr + pp * 64;
            *(short8*)&As[row * LDSP + sc] =
                *(const short8*)(xb + (size_t)toks[row] * DDIM + k0 + sc);
            *(short8*)&Bs[row * LDSP + sc] =
                *(const short8*)(W + (size_t)(n0 + row) * DDIM + k0 + sc);
        }
        __syncthreads();
        short8 af[4], bf[4];
        #pragma unroll
        for (int m = 0; m < 4; m++) af[m] = *(const short8*)&As[(mbase + m * 16 + lc) * LDSP + q * 8];
        #pragma unroll
        for (int n = 0; n < 4; n++) bf[n] = *(const short8*)&Bs[(nbase + n * 16 + lc) * LDSP + q * 8];
        #pragma unroll
        for (int m = 0; m < 4; m++)
            #pragma unroll
            for (int n = 0; n < 4; n++)
                acc[m][n] = __builtin_amdgcn_mfma_f32_16x16x32_bf16(af[m], bf[n], acc[m][n], 0, 0, 0);
        __syncthreads();
    }

    #pragma unroll
    for (int n = 0; n < 4; n++) {
        const int col = n0 + nbase + n * 16 + lc;
        const float bb = Bv[col];
        #pragma unroll
        for (int m = 0; m < 4; m++) {
            const int rbase = slot_base + mbase + m * 16 + q * 4;
            #pragma unroll
            for (int r = 0; r < 4; r++) {
                float v = acc[m][n][r] + bb;
                hh[(size_t)(rbase + r) * HDIM + col] = f2b(gelu_exact(v));
            }
        }
    }
}

// ---------------- GEMM2: eo[slot][d] = hh[slot] @ W2t^T + b2 (bf16, unweighted) ----------------
__global__ __launch_bounds__(256) void gemm2_kernel(
    const short* __restrict__ hh,
    const short* __restrict__ w2t, const float* __restrict__ b2,
    const short* __restrict__ ws2t, const float* __restrict__ bs2,
    const int* __restrict__ ntl, const int* __restrict__ offs,
    short* __restrict__ eo)
{
    const int e = blockIdx.z;
    if ((int)blockIdx.y >= ntl[e]) return;
    const int slot_base = offs[e] + blockIdx.y * MTILE;
    const int n0 = blockIdx.x * NTILE;
    const short* __restrict__ W  = (e < NEXP) ? (w2t + (size_t)e * HDIM * DDIM) : ws2t;  // [DDIM][HDIM]
    const float* __restrict__ Bv = (e < NEXP) ? (b2 + (size_t)e * DDIM) : bs2;

    __shared__ __align__(16) short As[MTILE * LDSP];
    __shared__ __align__(16) short Bs[NTILE * LDSP];

    const int tid = threadIdx.x;
    const int lane = tid & 63, wave = tid >> 6;
    const int mbase = (wave & 1) * 64, nbase = (wave >> 1) * 64;
    const int lc = lane & 15, q = lane >> 4;
    const int sr = tid >> 2, sc = (tid & 3) * 8;

    floatx4 acc[4][4];
    #pragma unroll
    for (int m = 0; m < 4; m++)
        #pragma unroll
        for (int n = 0; n < 4; n++) acc[m][n] = (floatx4)0.f;

    for (int k0 = 0; k0 < HDIM; k0 += KTILE) {
        #pragma unroll
        for (int pp = 0; pp < 2; pp++) {
            int row = sr + pp * 64;
            *(short8*)&As[row * LDSP + sc] =
                *(const short8*)(hh + (size_t)(slot_base + row) * HDIM + k0 + sc);
            *(short8*)&Bs[row * LDSP + sc] =
                *(const short8*)(W + (size_t)(n0 + row) * HDIM + k0 + sc);
        }
        __syncthreads();
        short8 af[4], bf[4];
        #pragma unroll
        for (int m = 0; m < 4; m++) af[m] = *(const short8*)&As[(mbase + m * 16 + lc) * LDSP + q * 8];
        #pragma unroll
        for (int n = 0; n < 4; n++) bf[n] = *(const short8*)&Bs[(nbase + n * 16 + lc) * LDSP + q * 8];
        #pragma unroll
        for (int m = 0; m < 4; m++)
            #pragma unroll
            for (int n = 0; n < 4; n++)
                acc[m][n] = __builtin_amdgcn_mfma_f32_16x16x32_bf16(af[m], bf[n], acc[m][n], 0, 0, 0);
        __syncthreads();
    }

    #pragma unroll
    for (int n = 0; n < 4; n++) {
        const int col = n0 + nbase + n * 16 + lc;
        const float bb = Bv[col];
        #pragma unroll
        for (int m = 0; m < 4; m++) {
            const int rbase = slot_base + mbase + m * 16 + q * 4;
            #pragma unroll
            for (int r = 0; r < 4; r++)
                eo[(size_t)(rbase + r) * DDIM + col] = f2b(acc[m][n][r] + bb);
        }
    }
}

// ---------------- combine: out[t] = eo[shared] + sum_k tw_k * eo[slot_k] ----------------
__global__ __launch_bounds__(256) void combine_kernel(
    const short* __restrict__ eo, const float* __restrict__ top_w,
    const int* __restrict__ slot_of, float* __restrict__ out)
{
    const int t = blockIdx.x;
    const int c = threadIdx.x * 4;
    const int s0 = slot_of[t * 4 + 0], s1 = slot_of[t * 4 + 1];
    const int s2 = slot_of[t * 4 + 2], s3 = slot_of[t * 4 + 3];
    const float w0 = top_w[t * 3 + 0], w1 = top_w[t * 3 + 1], w2 = top_w[t * 3 + 2];
    short4v a = *(const short4v*)(eo + (size_t)s0 * DDIM + c);
    short4v b = *(const short4v*)(eo + (size_t)s1 * DDIM + c);
    short4v d = *(const short4v*)(eo + (size_t)s2 * DDIM + c);
    short4v s = *(const short4v*)(eo + (size_t)s3 * DDIM + c);
    float4 o;
    o.x = b2f(s.x) + w0 * b2f(a.x) + w1 * b2f(b.x) + w2 * b2f(d.x);
    o.y = b2f(s.y) + w0 * b2f(a.y) + w1 * b2f(b.y) + w2 * b2f(d.y);
    o.z = b2f(s.z) + w0 * b2f(a.z) + w1 * b2f(b.z) + w2 * b2f(d.z);
    o.w = b2f(s.w) + w0 * b2f(a.w) + w1 * b2f(b.w) + w2 * b2f(d.w);
    *(float4*)(out + (size_t)t * DDIM + c) = o;
}

// ---------------- aux loss ----------------
__global__ __launch_bounds__(256) void preduce_kernel(const float* __restrict__ gwn, float* __restrict__ Pf) {
    __shared__ float sP[NEXP];
    if (threadIdx.x < NEXP) sP[threadIdx.x] = 0.f;
    __syncthreads();
    int t = blockIdx.x * blockDim.x + threadIdx.x;
    if (t < T_TOK) {
        #pragma unroll
        for (int e = 0; e < NEXP; e++) atomicAdd(&sP[e], gwn[(size_t)t * NEXP + e]);
    }
    __syncthreads();
    if (threadIdx.x < NEXP) atomicAdd(&Pf[threadIdx.x], sP[threadIdx.x]);
}

__global__ void aux_kernel(const float* __restrict__ Pf, const int* __restrict__ counts,
                           float* __restrict__ out_aux) {
    if (threadIdx.x == 0 && blockIdx.x == 0) {
        float aux = 0.f;
        for (int e = 0; e < NEXP; e++) {
            float P = Pf[e] / (float)T_TOK;
            float F = (float)NEXP * (float)counts[e] / (float)(TOPK * T_TOK);
            aux += P * F;
        }
        out_aux[0] = aux;
    }
}

extern "C" void kernel_launch(void* const* d_in, const int* in_sizes, int n_in,
                              void* d_out, int out_size, void* d_ws, size_t ws_size,
                              hipStream_t stream)
{
    const float* x   = (const float*)d_in[0];
    const float* gw  = (const float*)d_in[1];
    const float* gb  = (const float*)d_in[2];
    const float* w1  = (const float*)d_in[3];
    const float* b1  = (const float*)d_in[4];
    const float* w2  = (const float*)d_in[5];
    const float* b2  = (const float*)d_in[6];
    const float* ws1 = (const float*)d_in[7];
    const float* bs1 = (const float*)d_in[8];
    const float* ws2 = (const float*)d_in[9];
    const float* bs2 = (const float*)d_in[10];
    float* out = (float*)d_out;

    char* p = (char*)d_ws;
    auto alloc = [&](size_t bytes) -> char* {
        char* r = p; p += (bytes + 255) & ~(size_t)255; return r;
    };
    float* gwn      = (float*)alloc((size_t)T_TOK * NEXP * 4);
    int*   top_idx  = (int*)  alloc((size_t)T_TOK * 3 * 4);
    float* top_w    = (float*)alloc((size_t)T_TOK * 3 * 4);
    int*   meta     = (int*)  alloc(2 * NEXP * 4);   // counts | Pf (one memset)
    int*   counts   = meta;
    float* Pf       = (float*)(meta + NEXP);
    int*   offs     = (int*)  alloc((NEXP + 2) * 4);
    int*   ntl      = (int*)  alloc((NEXP + 1) * 4);
    int*   bhist    = (int*)  alloc((size_t)NBLK_T * NEXP * 4);
    int*   bbase    = (int*)  alloc((size_t)NBLK_T * NEXP * 4);
    int*   slot_t   = (int*)  alloc((size_t)MAX_SLOTS * 4);
    int*   slot_of  = (int*)  alloc((size_t)T_TOK * 4 * 4);
    float* gwT      = (float*)alloc((size_t)24 * DDIM * 4);    // 24 rows: expert 23 = zero pad
    short* xb       = (short*)alloc((size_t)T_TOK * DDIM * 2);
    short* w1t      = (short*)alloc((size_t)NEXP * DDIM * HDIM * 2);
    short* ws1t     = (short*)alloc((size_t)DDIM * HDIM * 2);
    short* w2t      = (short*)alloc((size_t)NEXP * DDIM * HDIM * 2);
    short* ws2t     = (short*)alloc((size_t)DDIM * HDIM * 2);
    short* hh       = (short*)alloc((size_t)MAX_SLOTS * HDIM * 2);
    short* eo       = (short*)alloc((size_t)MAX_SLOTS * DDIM * 2);

    hipMemsetAsync(meta, 0, 2 * NEXP * 4, stream);

    gwt_kernel<<<DDIM / 32, 256, 0, stream>>>(gw, gwT);
    prep_w_kernel<<<dim3(32, 16, 2 * (NEXP + 1)), 256, 0, stream>>>(
        w1, ws1, w2, ws2, w1t, ws1t, w2t, ws2t);
    xcvt_kernel<<<(T_TOK * DDIM / 4) / 256, 256, 0, stream>>>(x, xb);
    gate_kernel<<<GATE_BLOCKS, 256, 0, stream>>>(x, gwT, gb, gwn, top_idx, top_w);
    hist_kernel<<<NBLK_T, 256, 0, stream>>>(top_idx, bhist, counts);
    offsets_kernel<<<1, 256, 0, stream>>>(counts, bhist, offs, ntl, bbase, slot_t);
    scatter_kernel<<<NBLK_T, 256, 0, stream>>>(top_idx, offs, bbase, slot_t, slot_of);
    gemm1_kernel<<<dim3(HDIM / NTILE, MAX_TILES_PER_E, NEXP + 1), 256, 0, stream>>>(
        xb, w1t, b1, ws1t, bs1, ntl, offs, slot_t, hh);
    gemm2_kernel<<<dim3(DDIM / NTILE, MAX_TILES_PER_E, NEXP + 1), 256, 0, stream>>>(
        hh, w2t, b2, ws2t, bs2, ntl, offs, eo);
    combine_kernel<<<T_TOK, 256, 0, stream>>>(eo, top_w, slot_of, out);
    preduce_kernel<<<(T_TOK + 255) / 256, 256, 0, stream>>>(gwn, Pf);
    aux_kernel<<<1, 64, 0, stream>>>(Pf, counts, out + (size_t)T_TOK * DDIM);
}